// Round 8
// baseline (1141.063 us; speedup 1.0000x reference)
//
#include <hip/hip_runtime.h>
#include <hip/hip_fp16.h>
#include <cstdint>
#include <cstddef>
#include <type_traits>

#define N_NODES 30000
#define N_EDGES 480000
#define N_EDGES_SL (N_EDGES + N_NODES) // 510000
#define IN_CH 128
#define HEADS1 5
#define C1 64
#define D1 (HEADS1 * C1) // 320
#define OUT_CH 64
#define PE_CNT 100000
#define NEG_SLOPE 0.2f

typedef _Float16 f16x8 __attribute__((ext_vector_type(8)));
typedef _Float16 f16x2 __attribute__((ext_vector_type(2)));
typedef float fx4 __attribute__((ext_vector_type(4)));

#if defined(__has_builtin)
#if __has_builtin(__builtin_amdgcn_fdot2)
#define HAS_FDOT2 1
#endif
#endif

static __device__ __forceinline__ float leaky(float x) {
    return x > 0.f ? x : NEG_SLOPE * x;
}

// ---------------- device-scope grid barrier ----------------
// Same scheme ROCm cooperative grid.sync uses: release fence (L2 writeback) +
// device-scope atomic arrive + acquire spin + acquire fence (cache invalidate).
// Safe only because grid <= occupancy-query co-residency (see kernel_launch).
static __device__ __forceinline__ void grid_bar(int* ctr, int nb) {
    __syncthreads();
    if (threadIdx.x == 0) {
        __threadfence();
        __hip_atomic_fetch_add(ctr, 1, __ATOMIC_ACQ_REL, __HIP_MEMORY_SCOPE_AGENT);
        while (__hip_atomic_load(ctr, __ATOMIC_ACQUIRE, __HIP_MEMORY_SCOPE_AGENT) < nb)
            __builtin_amdgcn_s_sleep(2);
    }
    __syncthreads();
    __threadfence();
}

// ---------------- barrier-free MFMA fp16 GEMM phase + fused attention scores ----------------
// One wave-slot per 16-row tile (30000 = 16*1875). No LDS, no block barriers.
// mfma_f32_16x16x32_f16 layouts (HW-verified): A: lane holds A[m=lane&15][k=quad*8+j];
// B: lane holds B[k=quad*8+j][n=lane&15] (contiguous in Wt[n][k]); D: D[row=quad*4+reg][col=lane&15].
// Scores written HEAD-MAJOR: as_out[h*N_NODES + row].
template<int NH, typename AT>
static __device__ __forceinline__ void gemm_phase(const AT* __restrict__ A,
                                                  const __half* __restrict__ Wt,
                                                  __half* __restrict__ C, int K,
                                                  const float* __restrict__ att_src,
                                                  const float* __restrict__ att_dst,
                                                  float* __restrict__ as_out,
                                                  float* __restrict__ ad_out,
                                                  int slot, int nsl, int lane) {
    const int N = NH * 64;
    int q = lane >> 4, l16 = lane & 15;
    for (int tile = slot; tile < N_NODES / 16; tile += nsl) {
        int rowBase = tile * 16;
        int arow = rowBase + l16;
        fx4 zero4 = {0.f, 0.f, 0.f, 0.f};
        fx4 acc[NH][4];
#pragma unroll
        for (int h = 0; h < NH; ++h)
#pragma unroll
            for (int c = 0; c < 4; ++c) acc[h][c] = zero4;
        for (int kk = 0; kk < K; kk += 32) {
            f16x8 af;
            if constexpr (std::is_same<AT, float>::value) {
                const float4* s = (const float4*)(A + (size_t)arow * K + kk + q * 8);
                float4 v0 = s[0], v1 = s[1];
                af[0] = (_Float16)v0.x; af[1] = (_Float16)v0.y;
                af[2] = (_Float16)v0.z; af[3] = (_Float16)v0.w;
                af[4] = (_Float16)v1.x; af[5] = (_Float16)v1.y;
                af[6] = (_Float16)v1.z; af[7] = (_Float16)v1.w;
            } else {
                af = *(const f16x8*)((const __half*)A + (size_t)arow * K + kk + q * 8);
            }
#pragma unroll
            for (int h = 0; h < NH; ++h) {
#pragma unroll
                for (int c = 0; c < 4; ++c) {
                    int col = h * 64 + c * 16 + l16;
                    f16x8 bf = *(const f16x8*)(Wt + (size_t)col * K + kk + q * 8);
                    acc[h][c] = __builtin_amdgcn_mfma_f32_16x16x32_f16(af, bf, acc[h][c], 0, 0, 0);
                }
            }
        }
#pragma unroll
        for (int h = 0; h < NH; ++h) {
            float ps[4] = {0.f, 0.f, 0.f, 0.f};
            float pd[4] = {0.f, 0.f, 0.f, 0.f};
#pragma unroll
            for (int c = 0; c < 4; ++c) {
                int gcol = h * 64 + c * 16 + l16;
                float av = att_src[gcol];
                float dv = att_dst[gcol];
#pragma unroll
                for (int reg = 0; reg < 4; ++reg) {
                    int grow = rowBase + q * 4 + reg;
                    float val = acc[h][c][reg];
                    C[(size_t)grow * N + gcol] = __float2half(val);
                    ps[reg] += val * av;
                    pd[reg] += val * dv;
                }
            }
#pragma unroll
            for (int off = 1; off < 16; off <<= 1) {
#pragma unroll
                for (int reg = 0; reg < 4; ++reg) {
                    ps[reg] += __shfl_xor(ps[reg], off, 64);
                    pd[reg] += __shfl_xor(pd[reg], off, 64);
                }
            }
            if (l16 == 0) {
#pragma unroll
                for (int reg = 0; reg < 4; ++reg) {
                    int grow = rowBase + q * 4 + reg;
                    as_out[(size_t)h * N_NODES + grow] = ps[reg];
                    ad_out[(size_t)h * N_NODES + grow] = pd[reg];
                }
            }
        }
    }
}

// ---------------- fused softmax + weighted aggregate phase ----------------
// Wave-slot per (node,head), head-major items; grid-stride keeps a contiguous
// item window active -> preserves per-head-phase L2 locality.
// No max-subtract (inputs bounded; exp(e)/sum identical). Fast path deg<=64:
// lane=edge exp, w/j in per-wave LDS (same-wave RAW, no barrier); accumulate
// lane = es*8+cg with 2 independent 16B gathers in flight; LDS pad-9 transpose
// reduce -> all 64 lanes do the epilogue.
template<int NH, bool RELU>
static __device__ __forceinline__ void agg_phase(const int* __restrict__ row_ptr,
                                                 const int* __restrict__ esrc,
                                                 const __half* __restrict__ hf,   // [N][NH*64]
                                                 const float* __restrict__ a_src, // [NH][N]
                                                 const float* __restrict__ a_dst, // [NH][N]
                                                 const float* __restrict__ bias,  // [NH*64]
                                                 __half* __restrict__ zout,       // [N][NH*64]
                                                 int slot, int nsl, int lane, int wv,
                                                 float (*wbuf)[64], int (*jbuf)[64],
                                                 float (*red)[584]) {
    const int RS = NH * 64;
    int es = lane >> 3, cg = lane & 7;
    for (int wid = slot; wid < N_NODES * NH; wid += nsl) {
        int h = wid / N_NODES;
        int node = wid - h * N_NODES;
        int start = row_ptr[node], end = row_ptr[node + 1];
        int deg = end - start;
        const float* asrc_h = a_src + (size_t)h * N_NODES;
        float adst = a_dst[(size_t)h * N_NODES + node];
        const __half* hbase = hf + h * 64 + cg * 8;
        float acc[8] = {};
        float r;
        if (deg <= 64) {
            int j = 0;
            float ex = 0.f;
            if (lane < deg) {
                j = esrc[start + lane];
                ex = __expf(leaky(asrc_h[j] + adst));
            }
            float s = ex;
#pragma unroll
            for (int off = 1; off < 64; off <<= 1)
                s += __shfl_xor(s, off, 64);
            wbuf[wv][lane] = ex;
            jbuf[wv][lane] = j;
            r = 1.f / (s + 1e-16f);
            for (int k0 = 0; k0 < deg; k0 += 16) {
                int kA = k0 + es, kB = k0 + 8 + es;
                bool okA = kA < deg, okB = kB < deg;
                float wA = okA ? wbuf[wv][kA] : 0.f;
                float wB = okB ? wbuf[wv][kB] : 0.f;
                int jA = jbuf[wv][okA ? kA : 0];
                int jB = jbuf[wv][okB ? kB : 0];
                float4 vA = *(const float4*)(hbase + (size_t)jA * RS);
                float4 vB = *(const float4*)(hbase + (size_t)jB * RS);
                const __half2* pA = (const __half2*)&vA;
                const __half2* pB = (const __half2*)&vB;
#pragma unroll
                for (int i = 0; i < 4; ++i) {
                    float2 fA = __half22float2(pA[i]);
                    float2 fB = __half22float2(pB[i]);
                    acc[2 * i]     += wA * fA.x + wB * fB.x;
                    acc[2 * i + 1] += wA * fA.y + wB * fB.y;
                }
            }
        } else { // rare deg>64 path
            float s = 0.f;
            for (int k = start + lane; k < end; k += 64)
                s += __expf(leaky(asrc_h[esrc[k]] + adst));
#pragma unroll
            for (int off = 1; off < 64; off <<= 1)
                s += __shfl_xor(s, off, 64);
            r = 1.f / (s + 1e-16f);
            for (int k0 = start; k0 < end; k0 += 16) {
                int kA = k0 + es, kB = k0 + 8 + es;
                bool okA = kA < end, okB = kB < end;
                int jA = esrc[okA ? kA : start];
                int jB = esrc[okB ? kB : start];
                float wA = okA ? __expf(leaky(asrc_h[jA] + adst)) : 0.f;
                float wB = okB ? __expf(leaky(asrc_h[jB] + adst)) : 0.f;
                float4 vA = *(const float4*)(hbase + (size_t)jA * RS);
                float4 vB = *(const float4*)(hbase + (size_t)jB * RS);
                const __half2* pA = (const __half2*)&vA;
                const __half2* pB = (const __half2*)&vB;
#pragma unroll
                for (int i = 0; i < 4; ++i) {
                    float2 fA = __half22float2(pA[i]);
                    float2 fB = __half22float2(pB[i]);
                    acc[2 * i]     += wA * fA.x + wB * fB.x;
                    acc[2 * i + 1] += wA * fA.y + wB * fB.y;
                }
            }
        }
#pragma unroll
        for (int i = 0; i < 8; ++i)
            red[wv][(cg * 8 + i) * 9 + es] = acc[i];
        float tot = 0.f;
#pragma unroll
        for (int e2 = 0; e2 < 8; ++e2)
            tot += red[wv][lane * 9 + e2];
        float o = tot * r + bias[h * 64 + lane];
        if (RELU) o = fmaxf(o, 0.f);
        zout[(size_t)node * RS + h * 64 + lane] = __float2half(o);
    }
}

// ================ megakernel A: CSR build + weight prep + layer-1 GEMM ================
__global__ __launch_bounds__(256, 2) void megaA(
    const int* __restrict__ edge,
    const float* __restrict__ W1, const float* __restrict__ W2,
    __half* __restrict__ Wt1, __half* __restrict__ Wt2,
    const float* __restrict__ x, __half* __restrict__ h1,
    const float* __restrict__ att_src1, const float* __restrict__ att_dst1,
    float* __restrict__ as1, float* __restrict__ ad1,
    int* __restrict__ cnt, int* __restrict__ cursor,
    int* __restrict__ partial, int* __restrict__ ctr,
    int* __restrict__ row_ptr, int* __restrict__ esrc) {
    const int nb = gridDim.x;
    const int t = blockIdx.x * 256 + threadIdx.x;
    const int nthr = nb * 256;
    const int lane = threadIdx.x & 63;
    const int wv = threadIdx.x >> 6;

    // P0: degree count + weight transpose/cast (independent, same phase)
    for (int e = t; e < N_EDGES_SL; e += nthr) {
        int d = (e < N_EDGES) ? edge[N_EDGES + e] : (e - N_EDGES);
        atomicAdd(&cnt[d], 1);
    }
    const int T1 = IN_CH * D1, T2 = D1 * OUT_CH;
    for (int idx = t; idx < T1 + T2; idx += nthr) {
        if (idx < T1) {
            int k = idx / D1, n = idx - k * D1;
            Wt1[(size_t)n * IN_CH + k] = __float2half(W1[idx]);
        } else {
            int i2 = idx - T1;
            int k = i2 / OUT_CH, n = i2 - k * OUT_CH;
            Wt2[(size_t)n * D1 + k] = __float2half(W2[i2]);
        }
    }
    grid_bar(ctr + 0, nb);

    // P1: per-block partial sums of cnt over a contiguous slice
    const int S = (N_NODES + nb - 1) / nb; // nb >= 256 -> S <= 118 <= 256
    {
        int lo = blockIdx.x * S;
        int hi = lo + S; if (hi > N_NODES) hi = N_NODES;
        int s = 0;
        for (int i = lo + threadIdx.x; i < hi; i += 256) s += cnt[i];
#pragma unroll
        for (int off = 1; off < 64; off <<= 1) s += __shfl_xor(s, off, 64);
        __shared__ int r4[4];
        if (lane == 0) r4[wv] = s;
        __syncthreads();
        if (threadIdx.x == 0) partial[blockIdx.x] = r4[0] + r4[1] + r4[2] + r4[3];
    }
    grid_bar(ctr + 1, nb);

    // P2: block0 exclusive-scans partial[]; everyone else runs layer-1 GEMM
    if (blockIdx.x == 0) {
        __shared__ int wq[4];
        __shared__ int baseS;
        if (threadIdx.x == 0) baseS = 0;
        __syncthreads();
        for (int c0 = 0; c0 < nb; c0 += 256) {
            int i = c0 + threadIdx.x;
            int v = (i < nb) ? partial[i] : 0;
            int inc = v;
#pragma unroll
            for (int off = 1; off < 64; off <<= 1) {
                int u = __shfl_up(inc, off, 64);
                if (lane >= off) inc += u;
            }
            if (lane == 63) wq[wv] = inc;
            __syncthreads();
            int wb = 0;
#pragma unroll
            for (int k = 0; k < 4; ++k) wb += (k < wv) ? wq[k] : 0;
            int exc = baseS + wb + inc - v;
            if (i < nb) partial[i] = exc;
            __syncthreads();
            if (threadIdx.x == 255) baseS = exc + v;
            __syncthreads();
        }
        if (threadIdx.x == 0) row_ptr[N_NODES] = baseS;
    } else {
        int slot = (blockIdx.x - 1) * 4 + wv;
        int nsl = (nb - 1) * 4;
        gemm_phase<HEADS1, float>(x, Wt1, h1, IN_CH, att_src1, att_dst1, as1, ad1,
                                  slot, nsl, lane);
    }
    grid_bar(ctr + 2, nb);

    // P3: slice exclusive scan -> row_ptr
    {
        int lo = blockIdx.x * S;
        int i = lo + threadIdx.x;
        bool act = (threadIdx.x < S && i < N_NODES);
        int v = act ? cnt[i] : 0;
        int inc = v;
#pragma unroll
        for (int off = 1; off < 64; off <<= 1) {
            int u = __shfl_up(inc, off, 64);
            if (lane >= off) inc += u;
        }
        __shared__ int wq2[4];
        if (lane == 63) wq2[wv] = inc;
        __syncthreads();
        int wb = 0;
#pragma unroll
        for (int k = 0; k < 4; ++k) wb += (k < wv) ? wq2[k] : 0;
        if (act) row_ptr[i] = partial[blockIdx.x] + wb + inc - v;
    }
    grid_bar(ctr + 3, nb);

    // P4: scatter edges into CSR
    for (int e = t; e < N_EDGES_SL; e += nthr) {
        int s, d;
        if (e < N_EDGES) { s = edge[e]; d = edge[N_EDGES + e]; }
        else { s = e - N_EDGES; d = s; }
        int pos = row_ptr[d] + atomicAdd(&cursor[d], 1);
        esrc[pos] = s;
    }
}

// ================ megakernel B: agg1 -> gemm2 -> agg2 -> decode ================
__global__ __launch_bounds__(256, 6) void megaB(
    const int* __restrict__ row_ptr, const int* __restrict__ esrc,
    const __half* __restrict__ h1, const float* __restrict__ as1, const float* __restrict__ ad1,
    const float* __restrict__ b1, __half* __restrict__ z1,
    const __half* __restrict__ Wt2, __half* __restrict__ h2,
    const float* __restrict__ att_src2, const float* __restrict__ att_dst2,
    float* __restrict__ as2, float* __restrict__ ad2,
    const float* __restrict__ b2, __half* __restrict__ z2,
    const int* __restrict__ pos, const int* __restrict__ neg,
    float* __restrict__ out, int* __restrict__ ctr) {
    __shared__ float wbuf[4][64];
    __shared__ int jbuf[4][64];
    __shared__ float red[4][584];
    const int nb = gridDim.x;
    const int lane = threadIdx.x & 63;
    const int wv = threadIdx.x >> 6;
    const int slot = blockIdx.x * 4 + wv;
    const int nsl = nb * 4;

    agg_phase<HEADS1, true>(row_ptr, esrc, h1, as1, ad1, b1, z1,
                            slot, nsl, lane, wv, wbuf, jbuf, red);
    grid_bar(ctr + 0, nb);
    gemm_phase<1, __half>(z1, Wt2, h2, D1, att_src2, att_dst2, as2, ad2,
                          slot, nsl, lane);
    grid_bar(ctr + 1, nb);
    agg_phase<1, false>(row_ptr, esrc, h2, as2, ad2, b2, z2,
                        slot, nsl, lane, wv, wbuf, jbuf, red);
    grid_bar(ctr + 2, nb);
    // decode: 8 lanes per edge, 16B fp16 loads
    for (int it = slot; it < (2 * PE_CNT) / 8; it += nsl) {
        int e = it * 8 + (lane >> 3);
        int lc = lane & 7;
        int a, b;
        if (e < PE_CNT) { a = pos[e]; b = pos[PE_CNT + e]; }
        else { int k = e - PE_CNT; a = neg[k]; b = neg[PE_CNT + k]; }
        union U { float4 f; f16x2 h[4]; __half2 hh[4]; } ua, ub;
        ua.f = *(const float4*)(z2 + (size_t)a * OUT_CH + lc * 8);
        ub.f = *(const float4*)(z2 + (size_t)b * OUT_CH + lc * 8);
        float v = 0.f;
#pragma unroll
        for (int i = 0; i < 4; ++i) {
#ifdef HAS_FDOT2
            v = __builtin_amdgcn_fdot2(ua.h[i], ub.h[i], v, false);
#else
            float2 fa = __half22float2(ua.hh[i]);
            float2 fb = __half22float2(ub.hh[i]);
            v += fa.x * fb.x + fa.y * fb.y;
#endif
        }
#pragma unroll
        for (int off = 1; off < 8; off <<= 1)
            v += __shfl_xor(v, off, 64);
        if (lc == 0) out[e] = v;
    }
}

extern "C" void kernel_launch(void* const* d_in, const int* in_sizes, int n_in,
                              void* d_out, int out_size, void* d_ws, size_t ws_size,
                              hipStream_t stream) {
    const float* x        = (const float*)d_in[0];
    const int* edge_index = (const int*)d_in[1];
    const int* pos_ei     = (const int*)d_in[2];
    const int* neg_ei     = (const int*)d_in[3];
    const float* W1       = (const float*)d_in[4];
    const float* att_src1 = (const float*)d_in[5];
    const float* att_dst1 = (const float*)d_in[6];
    const float* b1       = (const float*)d_in[7];
    const float* W2       = (const float*)d_in[8];
    const float* att_src2 = (const float*)d_in[9];
    const float* att_dst2 = (const float*)d_in[10];
    const float* b2       = (const float*)d_in[11];
    float* out            = (float*)d_out;

    char* ws = (char*)d_ws;
    size_t off = 0;
    auto alloc = [&](size_t bytes) -> void* {
        void* p = ws + off;
        off = (off + bytes + 255) & ~(size_t)255;
        return p;
    };
    // int scratch first: [cnt | cursor | partial | ctrA(8) | ctrB(8)] zeroed by ONE memset
    const size_t NI = (size_t)2 * N_NODES + 2048 + 16;
    int* iscratch = (int*)alloc(sizeof(int) * NI);
    int* cnt     = iscratch;
    int* cursor  = cnt + N_NODES;
    int* partial = cursor + N_NODES;
    int* ctrA    = partial + 2048;
    int* ctrB    = ctrA + 8;
    int* row_ptr = (int*)alloc(sizeof(int) * (N_NODES + 1));
    int* esrc    = (int*)alloc(sizeof(int) * (size_t)N_EDGES_SL);
    __half* h1   = (__half*)alloc(sizeof(__half) * (size_t)N_NODES * D1);
    __half* z1   = (__half*)alloc(sizeof(__half) * (size_t)N_NODES * D1);
    __half* h2   = (__half*)alloc(sizeof(__half) * (size_t)N_NODES * OUT_CH);
    __half* z2   = (__half*)alloc(sizeof(__half) * (size_t)N_NODES * OUT_CH);
    __half* Wt1  = (__half*)alloc(sizeof(__half) * (size_t)D1 * IN_CH);
    __half* Wt2  = (__half*)alloc(sizeof(__half) * (size_t)OUT_CH * D1);
    float* as1   = (float*)alloc(sizeof(float) * (size_t)N_NODES * HEADS1); // [h][N]
    float* ad1   = (float*)alloc(sizeof(float) * (size_t)N_NODES * HEADS1); // [h][N]
    float* as2   = (float*)alloc(sizeof(float) * (size_t)N_NODES);
    float* ad2   = (float*)alloc(sizeof(float) * (size_t)N_NODES);

    // co-residency-safe grid sizes (manual grid barrier requires all blocks resident)
    int occA = 0, occB = 0;
    (void)hipOccupancyMaxActiveBlocksPerMultiprocessor(&occA, megaA, 256, 0);
    (void)hipOccupancyMaxActiveBlocksPerMultiprocessor(&occB, megaB, 256, 0);
    if (occA < 1) occA = 1;
    if (occB < 1) occB = 1;
    int nbA = occA * 256; if (nbA > 2048) nbA = 2048;
    int nbB = occB * 256; if (nbB > 2048) nbB = 2048;

    hipMemsetAsync(iscratch, 0, sizeof(int) * NI, stream);
    megaA<<<nbA, 256, 0, stream>>>(edge_index, W1, W2, Wt1, Wt2,
                                   x, h1, att_src1, att_dst1, as1, ad1,
                                   cnt, cursor, partial, ctrA, row_ptr, esrc);
    megaB<<<nbB, 256, 0, stream>>>(row_ptr, esrc, h1, as1, ad1, b1, z1,
                                   Wt2, h2, att_src2, att_dst2, as2, ad2, b2, z2,
                                   pos_ei, neg_ei, out, ctrB);

    (void)in_sizes; (void)n_in; (void)out_size; (void)ws_size;
}

// Round 9
// 295.631 us; speedup vs baseline: 3.8598x; 3.8598x over previous
//
#include <hip/hip_runtime.h>
#include <hip/hip_fp16.h>
#include <cstdint>
#include <cstddef>
#include <type_traits>

#define N_NODES 30000
#define N_EDGES 480000
#define N_EDGES_SL (N_EDGES + N_NODES) // 510000
#define IN_CH 128
#define HEADS1 5
#define C1 64
#define D1 (HEADS1 * C1) // 320
#define OUT_CH 64
#define PE_CNT 100000
#define NEG_SLOPE 0.2f

typedef _Float16 f16x8 __attribute__((ext_vector_type(8)));
typedef _Float16 f16x2 __attribute__((ext_vector_type(2)));
typedef float fx4 __attribute__((ext_vector_type(4)));

#if defined(__has_builtin)
#if __has_builtin(__builtin_amdgcn_fdot2)
#define HAS_FDOT2 1
#endif
#endif

static __device__ __forceinline__ float leaky(float x) {
    return x > 0.f ? x : NEG_SLOPE * x;
}

// ---------------- barrier-free MFMA fp16 GEMM phase + fused attention scores ----------------
// Wave-slot per 16-row tile (30000 = 16*1875). No LDS, no barriers.
// mfma_f32_16x16x32_f16 layouts (HW-verified): A: lane holds A[m=lane&15][k=quad*8+j];
// B: lane holds B[k=quad*8+j][n=lane&15] (contiguous in Wt[n][k]); D: D[row=quad*4+reg][col=lane&15].
// Scores written HEAD-MAJOR: as_out[h*N_NODES + row].
template<int NH, typename AT>
static __device__ __forceinline__ void gemm_phase(const AT* __restrict__ A,
                                                  const __half* __restrict__ Wt,
                                                  __half* __restrict__ C, int K,
                                                  const float* __restrict__ att_src,
                                                  const float* __restrict__ att_dst,
                                                  float* __restrict__ as_out,
                                                  float* __restrict__ ad_out,
                                                  int slot, int nsl, int lane) {
    const int N = NH * 64;
    int q = lane >> 4, l16 = lane & 15;
    for (int tile = slot; tile < N_NODES / 16; tile += nsl) {
        int rowBase = tile * 16;
        int arow = rowBase + l16;
        fx4 zero4 = {0.f, 0.f, 0.f, 0.f};
        fx4 acc[NH][4];
#pragma unroll
        for (int h = 0; h < NH; ++h)
#pragma unroll
            for (int c = 0; c < 4; ++c) acc[h][c] = zero4;
        for (int kk = 0; kk < K; kk += 32) {
            f16x8 af;
            if constexpr (std::is_same<AT, float>::value) {
                const float4* s = (const float4*)(A + (size_t)arow * K + kk + q * 8);
                float4 v0 = s[0], v1 = s[1];
                af[0] = (_Float16)v0.x; af[1] = (_Float16)v0.y;
                af[2] = (_Float16)v0.z; af[3] = (_Float16)v0.w;
                af[4] = (_Float16)v1.x; af[5] = (_Float16)v1.y;
                af[6] = (_Float16)v1.z; af[7] = (_Float16)v1.w;
            } else {
                af = *(const f16x8*)((const __half*)A + (size_t)arow * K + kk + q * 8);
            }
#pragma unroll
            for (int h = 0; h < NH; ++h) {
#pragma unroll
                for (int c = 0; c < 4; ++c) {
                    int col = h * 64 + c * 16 + l16;
                    f16x8 bf = *(const f16x8*)(Wt + (size_t)col * K + kk + q * 8);
                    acc[h][c] = __builtin_amdgcn_mfma_f32_16x16x32_f16(af, bf, acc[h][c], 0, 0, 0);
                }
            }
        }
#pragma unroll
        for (int h = 0; h < NH; ++h) {
            float ps[4] = {0.f, 0.f, 0.f, 0.f};
            float pd[4] = {0.f, 0.f, 0.f, 0.f};
#pragma unroll
            for (int c = 0; c < 4; ++c) {
                int gcol = h * 64 + c * 16 + l16;
                float av = att_src[gcol];
                float dv = att_dst[gcol];
#pragma unroll
                for (int reg = 0; reg < 4; ++reg) {
                    int grow = rowBase + q * 4 + reg;
                    float val = acc[h][c][reg];
                    C[(size_t)grow * N + gcol] = __float2half(val);
                    ps[reg] += val * av;
                    pd[reg] += val * dv;
                }
            }
#pragma unroll
            for (int off = 1; off < 16; off <<= 1) {
#pragma unroll
                for (int reg = 0; reg < 4; ++reg) {
                    ps[reg] += __shfl_xor(ps[reg], off, 64);
                    pd[reg] += __shfl_xor(pd[reg], off, 64);
                }
            }
            if (l16 == 0) {
#pragma unroll
                for (int reg = 0; reg < 4; ++reg) {
                    int grow = rowBase + q * 4 + reg;
                    as_out[(size_t)h * N_NODES + grow] = ps[reg];
                    ad_out[(size_t)h * N_NODES + grow] = pd[reg];
                }
            }
        }
    }
}

// ================ K1: degree count || weight transpose/cast (independent) ================
__global__ __launch_bounds__(256) void k_count_prep(const int* __restrict__ edge,
                                                    int* __restrict__ cnt,
                                                    const float* __restrict__ W1,
                                                    __half* __restrict__ Wt1,
                                                    const float* __restrict__ W2,
                                                    __half* __restrict__ Wt2) {
    int t = blockIdx.x * 256 + threadIdx.x;
    int nthr = gridDim.x * 256;
    for (int e = t; e < N_EDGES_SL; e += nthr) {
        int d = (e < N_EDGES) ? edge[N_EDGES + e] : (e - N_EDGES);
        atomicAdd(&cnt[d], 1);
    }
    const int T1 = IN_CH * D1, T2 = D1 * OUT_CH;
    for (int idx = t; idx < T1 + T2; idx += nthr) {
        if (idx < T1) {
            int k = idx / D1, n = idx - k * D1;
            Wt1[(size_t)n * IN_CH + k] = __float2half(W1[idx]);
        } else {
            int i2 = idx - T1;
            int k = i2 / OUT_CH, n = i2 - k * OUT_CH;
            Wt2[(size_t)n * D1 + k] = __float2half(W2[i2]);
        }
    }
}

// ================ K2: block0 = serial CSR scan || rest = layer-1 GEMM ================
__global__ __launch_bounds__(256) void k_scan_gemm1(const int* __restrict__ cnt,
                                                    int* __restrict__ row_ptr,
                                                    const float* __restrict__ x,
                                                    const __half* __restrict__ Wt1,
                                                    __half* __restrict__ h1,
                                                    const float* __restrict__ att_src1,
                                                    const float* __restrict__ att_dst1,
                                                    float* __restrict__ as1,
                                                    float* __restrict__ ad1) {
    int lane = threadIdx.x & 63, wv = threadIdx.x >> 6;
    if (blockIdx.x == 0) {
        // 256-thread sequential chunk scan with carry (hides under gemm1)
        __shared__ int wsum[4];
        __shared__ int wexc[4];
        __shared__ int chtot;
        int t = threadIdx.x;
        int carry = 0;
        for (int base = 0; base < N_NODES; base += 256) {
            int i = base + t;
            int v = (i < N_NODES) ? cnt[i] : 0;
            int inc = v;
#pragma unroll
            for (int off = 1; off < 64; off <<= 1) {
                int u = __shfl_up(inc, off, 64);
                if (lane >= off) inc += u;
            }
            if (lane == 63) wsum[wv] = inc;
            __syncthreads();
            if (t == 0) {
                int s = 0;
#pragma unroll
                for (int k = 0; k < 4; ++k) { wexc[k] = s; s += wsum[k]; }
                chtot = s;
            }
            __syncthreads();
            if (i < N_NODES) row_ptr[i] = carry + wexc[wv] + inc - v;
            carry += chtot;
            __syncthreads();
        }
        if (t == 0) row_ptr[N_NODES] = carry;
    } else {
        int slot = (blockIdx.x - 1) * 4 + wv;
        int nsl = (gridDim.x - 1) * 4;
        gemm_phase<HEADS1, float>(x, Wt1, h1, IN_CH, att_src1, att_dst1, as1, ad1,
                                  slot, nsl, lane);
    }
}

// ================ K3: scatter edges into CSR ================
__global__ __launch_bounds__(256) void k_scatter(const int* __restrict__ edge,
                                                 const int* __restrict__ row_ptr,
                                                 int* __restrict__ cursor,
                                                 int* __restrict__ esrc) {
    int e = blockIdx.x * blockDim.x + threadIdx.x;
    if (e >= N_EDGES_SL) return;
    int s, d;
    if (e < N_EDGES) { s = edge[e]; d = edge[N_EDGES + e]; }
    else { s = e - N_EDGES; d = s; }
    int pos = row_ptr[d] + atomicAdd(&cursor[d], 1);
    esrc[pos] = s;
}

// ================ fused softmax + weighted aggregate ================
// wave per (node,head), HEAD-MAJOR grid; scores HEAD-MAJOR [h][N].
// No max-subtract (inputs bounded; exp/sum identical). Weights PRE-NORMALIZED
// by r (w' = exp*r in [0,1], no overflow) and packed to half2 in LDS once.
// Gather loop: lane = es*8+cg, 2 independent 16B loads/iter, __hfma2 packed
// fp16 accumulate (partial sums span only deg/8 ~ 2-3 terms). Cross-sublane
// reduce via LDS pad-9 transpose in fp32 -> all 64 lanes do the epilogue.
template<int NH, bool RELU>
__global__ __launch_bounds__(256) void k_attn_agg(const int* __restrict__ row_ptr,
                                                  const int* __restrict__ esrc,
                                                  const __half* __restrict__ hf,   // [N][NH*64]
                                                  const float* __restrict__ a_src, // [NH][N]
                                                  const float* __restrict__ a_dst, // [NH][N]
                                                  const float* __restrict__ bias,  // [NH*64]
                                                  __half* __restrict__ zout) {     // [N][NH*64]
    __shared__ unsigned wpk[4][64]; // packed half2 normalized weights
    __shared__ int jbuf[4][64];
    __shared__ float red[4][584];
    int wid = (blockIdx.x * 256 + threadIdx.x) >> 6;
    int lane = threadIdx.x & 63;
    int wv = threadIdx.x >> 6;
    if (wid >= N_NODES * NH) return;
    int h = wid / N_NODES;
    int node = wid - h * N_NODES;
    int start = row_ptr[node], end = row_ptr[node + 1];
    int deg = end - start;
    const float* asrc_h = a_src + (size_t)h * N_NODES;
    float adst = a_dst[(size_t)h * N_NODES + node];
    int es = lane >> 3, cg = lane & 7;
    const int RS = NH * 64;
    const __half* hbase = hf + h * 64 + cg * 8;
    __half2 acch[4] = {__half2{0, 0}, __half2{0, 0}, __half2{0, 0}, __half2{0, 0}};
    if (deg <= 64) {
        int j = 0;
        float ex = 0.f;
        if (lane < deg) {
            j = esrc[start + lane];
            ex = __expf(leaky(asrc_h[j] + adst));
        }
        float s = ex;
#pragma unroll
        for (int off = 1; off < 64; off <<= 1)
            s += __shfl_xor(s, off, 64);
        float r = 1.f / (s + 1e-16f);
        __half2 wn = __float2half2_rn(ex * r);
        wpk[wv][lane] = *(unsigned*)&wn;
        jbuf[wv][lane] = j;
        for (int k0 = 0; k0 < deg; k0 += 16) {
            int kA = k0 + es, kB = k0 + 8 + es;
            bool okA = kA < deg, okB = kB < deg;
            unsigned uA = okA ? wpk[wv][kA] : 0u;
            unsigned uB = okB ? wpk[wv][kB] : 0u;
            int jA = jbuf[wv][okA ? kA : 0];
            int jB = jbuf[wv][okB ? kB : 0];
            float4 vA = *(const float4*)(hbase + (size_t)jA * RS);
            float4 vB = *(const float4*)(hbase + (size_t)jB * RS);
            __half2 hwA = *(__half2*)&uA, hwB = *(__half2*)&uB;
            const __half2* pA = (const __half2*)&vA;
            const __half2* pB = (const __half2*)&vB;
#pragma unroll
            for (int i = 0; i < 4; ++i) {
                acch[i] = __hfma2(pA[i], hwA, acch[i]);
                acch[i] = __hfma2(pB[i], hwB, acch[i]);
            }
        }
    } else { // rare deg>64 path
        float s = 0.f;
        for (int k = start + lane; k < end; k += 64)
            s += __expf(leaky(asrc_h[esrc[k]] + adst));
#pragma unroll
        for (int off = 1; off < 64; off <<= 1)
            s += __shfl_xor(s, off, 64);
        float r = 1.f / (s + 1e-16f);
        for (int k0 = start; k0 < end; k0 += 16) {
            int kA = k0 + es, kB = k0 + 8 + es;
            bool okA = kA < end, okB = kB < end;
            int jA = esrc[okA ? kA : start];
            int jB = esrc[okB ? kB : start];
            float fA = okA ? __expf(leaky(asrc_h[jA] + adst)) * r : 0.f;
            float fB = okB ? __expf(leaky(asrc_h[jB] + adst)) * r : 0.f;
            __half2 hwA = __float2half2_rn(fA), hwB = __float2half2_rn(fB);
            float4 vA = *(const float4*)(hbase + (size_t)jA * RS);
            float4 vB = *(const float4*)(hbase + (size_t)jB * RS);
            const __half2* pA = (const __half2*)&vA;
            const __half2* pB = (const __half2*)&vB;
#pragma unroll
            for (int i = 0; i < 4; ++i) {
                acch[i] = __hfma2(pA[i], hwA, acch[i]);
                acch[i] = __hfma2(pB[i], hwB, acch[i]);
            }
        }
    }
    // fp32 cross-sublane reduce via LDS transpose (pad-9: 2-way conflicts = free)
#pragma unroll
    for (int i = 0; i < 4; ++i) {
        float2 f = __half22float2(acch[i]);
        red[wv][(cg * 8 + 2 * i) * 9 + es] = f.x;
        red[wv][(cg * 8 + 2 * i + 1) * 9 + es] = f.y;
    }
    float tot = 0.f;
#pragma unroll
    for (int e2 = 0; e2 < 8; ++e2)
        tot += red[wv][lane * 9 + e2];
    float o = tot + bias[h * 64 + lane];
    if (RELU) o = fmaxf(o, 0.f);
    zout[(size_t)node * RS + h * 64 + lane] = __float2half(o);
}

// ================ layer-2 GEMM (slot-strided, 256-thr blocks) ================
__global__ __launch_bounds__(256) void k_gemm2(const __half* __restrict__ z1,
                                               const __half* __restrict__ Wt2,
                                               __half* __restrict__ h2,
                                               const float* __restrict__ att_src2,
                                               const float* __restrict__ att_dst2,
                                               float* __restrict__ as2,
                                               float* __restrict__ ad2) {
    int lane = threadIdx.x & 63, wv = threadIdx.x >> 6;
    int slot = blockIdx.x * 4 + wv;
    int nsl = gridDim.x * 4;
    gemm_phase<1, __half>(z1, Wt2, h2, D1, att_src2, att_dst2, as2, ad2,
                          slot, nsl, lane);
}

// ================ decode: 8 lanes per edge, 16B fp16 loads, fdot2 ================
__global__ __launch_bounds__(256) void k_decode(const int* __restrict__ pos,
                                                const int* __restrict__ neg,
                                                const __half* __restrict__ z2,
                                                float* __restrict__ out) {
    int t = blockIdx.x * 256 + threadIdx.x;
    int e = t >> 3;
    int lc = t & 7;
    if (e >= 2 * PE_CNT) return;
    int a, b;
    if (e < PE_CNT) { a = pos[e]; b = pos[PE_CNT + e]; }
    else { int k = e - PE_CNT; a = neg[k]; b = neg[PE_CNT + k]; }
    union U { float4 f; f16x2 h[4]; __half2 hh[4]; } ua, ub;
    ua.f = *(const float4*)(z2 + (size_t)a * OUT_CH + lc * 8);
    ub.f = *(const float4*)(z2 + (size_t)b * OUT_CH + lc * 8);
    float v = 0.f;
#pragma unroll
    for (int i = 0; i < 4; ++i) {
#ifdef HAS_FDOT2
        v = __builtin_amdgcn_fdot2(ua.h[i], ub.h[i], v, false);
#else
        float2 fa = __half22float2(ua.hh[i]);
        float2 fb = __half22float2(ub.hh[i]);
        v += fa.x * fb.x + fa.y * fb.y;
#endif
    }
#pragma unroll
    for (int off = 1; off < 8; off <<= 1)
        v += __shfl_xor(v, off, 64);
    if (lc == 0) out[e] = v;
}

extern "C" void kernel_launch(void* const* d_in, const int* in_sizes, int n_in,
                              void* d_out, int out_size, void* d_ws, size_t ws_size,
                              hipStream_t stream) {
    const float* x        = (const float*)d_in[0];
    const int* edge_index = (const int*)d_in[1];
    const int* pos_ei     = (const int*)d_in[2];
    const int* neg_ei     = (const int*)d_in[3];
    const float* W1       = (const float*)d_in[4];
    const float* att_src1 = (const float*)d_in[5];
    const float* att_dst1 = (const float*)d_in[6];
    const float* b1       = (const float*)d_in[7];
    const float* W2       = (const float*)d_in[8];
    const float* att_src2 = (const float*)d_in[9];
    const float* att_dst2 = (const float*)d_in[10];
    const float* b2       = (const float*)d_in[11];
    float* out            = (float*)d_out;

    char* ws = (char*)d_ws;
    size_t off = 0;
    auto alloc = [&](size_t bytes) -> void* {
        void* p = ws + off;
        off = (off + bytes + 255) & ~(size_t)255;
        return p;
    };
    int* cnt     = (int*)alloc(sizeof(int) * (size_t)2 * N_NODES); // cnt+cursor: one memset
    int* cursor  = cnt + N_NODES;
    int* row_ptr = (int*)alloc(sizeof(int) * (N_NODES + 1));
    int* esrc    = (int*)alloc(sizeof(int) * (size_t)N_EDGES_SL);
    __half* h1   = (__half*)alloc(sizeof(__half) * (size_t)N_NODES * D1);
    __half* z1   = (__half*)alloc(sizeof(__half) * (size_t)N_NODES * D1);
    __half* h2   = (__half*)alloc(sizeof(__half) * (size_t)N_NODES * OUT_CH);
    __half* z2   = (__half*)alloc(sizeof(__half) * (size_t)N_NODES * OUT_CH);
    __half* Wt1  = (__half*)alloc(sizeof(__half) * (size_t)D1 * IN_CH);
    __half* Wt2  = (__half*)alloc(sizeof(__half) * (size_t)OUT_CH * D1);
    float* as1   = (float*)alloc(sizeof(float) * (size_t)N_NODES * HEADS1); // [h][N]
    float* ad1   = (float*)alloc(sizeof(float) * (size_t)N_NODES * HEADS1); // [h][N]
    float* as2   = (float*)alloc(sizeof(float) * (size_t)N_NODES);
    float* ad2   = (float*)alloc(sizeof(float) * (size_t)N_NODES);

    hipMemsetAsync(cnt, 0, sizeof(int) * (size_t)2 * N_NODES, stream);
    // K1: degree count || weight prep
    k_count_prep<<<512, 256, 0, stream>>>(edge_index, cnt, W1, Wt1, W2, Wt2);
    // K2: CSR scan (block 0) || layer-1 MFMA GEMM + scores (blocks 1..)
    k_scan_gemm1<<<470, 256, 0, stream>>>(cnt, row_ptr, x, Wt1, h1,
                                          att_src1, att_dst1, as1, ad1);
    // K3: scatter edges
    k_scatter<<<(N_EDGES_SL + 255) / 256, 256, 0, stream>>>(edge_index, row_ptr, cursor, esrc);
    // layer-1 softmax-aggregate (+relu)
    k_attn_agg<HEADS1, true><<<(N_NODES * HEADS1 + 3) / 4, 256, 0, stream>>>(
        row_ptr, esrc, h1, as1, ad1, b1, z1);
    // layer-2 GEMM + scores
    k_gemm2<<<469, 256, 0, stream>>>(z1, Wt2, h2, att_src2, att_dst2, as2, ad2);
    // layer-2 softmax-aggregate
    k_attn_agg<1, false><<<(N_NODES + 3) / 4, 256, 0, stream>>>(
        row_ptr, esrc, h2, as2, ad2, b2, z2);
    // decode
    k_decode<<<(2 * PE_CNT * 8 + 255) / 256, 256, 0, stream>>>(pos_ei, neg_ei, z2, out);

    (void)in_sizes; (void)n_in; (void)out_size; (void)ws_size;
}

// Round 10
// 248.511 us; speedup vs baseline: 4.5916x; 1.1896x over previous
//
#include <hip/hip_runtime.h>
#include <hip/hip_fp16.h>
#include <cstdint>
#include <cstddef>
#include <type_traits>

#define N_NODES 30000
#define N_EDGES 480000
#define N_EDGES_SL (N_EDGES + N_NODES) // 510000
#define IN_CH 128
#define HEADS1 5
#define C1 64
#define D1 (HEADS1 * C1) // 320
#define OUT_CH 64
#define PE_CNT 100000
#define NEG_SLOPE 0.2f

#define GEMM1_BLOCKS 469              // 469*4 = 1876 wave-slots for 1875 tiles
#define PART_BLOCKS ((N_NODES + 255) / 256) // 118

typedef _Float16 f16x8 __attribute__((ext_vector_type(8)));
typedef _Float16 f16x2 __attribute__((ext_vector_type(2)));
typedef float fx4 __attribute__((ext_vector_type(4)));

#if defined(__has_builtin)
#if __has_builtin(__builtin_amdgcn_fdot2)
#define HAS_FDOT2 1
#endif
#endif

static __device__ __forceinline__ float leaky(float x) {
    return x > 0.f ? x : NEG_SLOPE * x;
}

// ---------------- barrier-free MFMA fp16 GEMM phase + fused attention scores ----------------
// Wave-slot per 16-row tile (30000 = 16*1875). No LDS, no barriers.
// mfma_f32_16x16x32_f16 layouts (HW-verified): A: lane holds A[m=lane&15][k=quad*8+j];
// B: lane holds B[k=quad*8+j][n=lane&15] (contiguous in Wt[n][k]); D: D[row=quad*4+reg][col=lane&15].
// Scores written HEAD-MAJOR: as_out[h*N_NODES + row].
template<int NH, typename AT>
static __device__ __forceinline__ void gemm_phase(const AT* __restrict__ A,
                                                  const __half* __restrict__ Wt,
                                                  __half* __restrict__ C, int K,
                                                  const float* __restrict__ att_src,
                                                  const float* __restrict__ att_dst,
                                                  float* __restrict__ as_out,
                                                  float* __restrict__ ad_out,
                                                  int slot, int nsl, int lane) {
    const int N = NH * 64;
    int q = lane >> 4, l16 = lane & 15;
    for (int tile = slot; tile < N_NODES / 16; tile += nsl) {
        int rowBase = tile * 16;
        int arow = rowBase + l16;
        fx4 zero4 = {0.f, 0.f, 0.f, 0.f};
        fx4 acc[NH][4];
#pragma unroll
        for (int h = 0; h < NH; ++h)
#pragma unroll
            for (int c = 0; c < 4; ++c) acc[h][c] = zero4;
        for (int kk = 0; kk < K; kk += 32) {
            f16x8 af;
            if constexpr (std::is_same<AT, float>::value) {
                const float4* s = (const float4*)(A + (size_t)arow * K + kk + q * 8);
                float4 v0 = s[0], v1 = s[1];
                af[0] = (_Float16)v0.x; af[1] = (_Float16)v0.y;
                af[2] = (_Float16)v0.z; af[3] = (_Float16)v0.w;
                af[4] = (_Float16)v1.x; af[5] = (_Float16)v1.y;
                af[6] = (_Float16)v1.z; af[7] = (_Float16)v1.w;
            } else {
                af = *(const f16x8*)((const __half*)A + (size_t)arow * K + kk + q * 8);
            }
#pragma unroll
            for (int h = 0; h < NH; ++h) {
#pragma unroll
                for (int c = 0; c < 4; ++c) {
                    int col = h * 64 + c * 16 + l16;
                    f16x8 bf = *(const f16x8*)(Wt + (size_t)col * K + kk + q * 8);
                    acc[h][c] = __builtin_amdgcn_mfma_f32_16x16x32_f16(af, bf, acc[h][c], 0, 0, 0);
                }
            }
        }
#pragma unroll
        for (int h = 0; h < NH; ++h) {
            float ps[4] = {0.f, 0.f, 0.f, 0.f};
            float pd[4] = {0.f, 0.f, 0.f, 0.f};
#pragma unroll
            for (int c = 0; c < 4; ++c) {
                int gcol = h * 64 + c * 16 + l16;
                float av = att_src[gcol];
                float dv = att_dst[gcol];
#pragma unroll
                for (int reg = 0; reg < 4; ++reg) {
                    int grow = rowBase + q * 4 + reg;
                    float val = acc[h][c][reg];
                    C[(size_t)grow * N + gcol] = __float2half(val);
                    ps[reg] += val * av;
                    pd[reg] += val * dv;
                }
            }
#pragma unroll
            for (int off = 1; off < 16; off <<= 1) {
#pragma unroll
                for (int reg = 0; reg < 4; ++reg) {
                    ps[reg] += __shfl_xor(ps[reg], off, 64);
                    pd[reg] += __shfl_xor(pd[reg], off, 64);
                }
            }
            if (l16 == 0) {
#pragma unroll
                for (int reg = 0; reg < 4; ++reg) {
                    int grow = rowBase + q * 4 + reg;
                    as_out[(size_t)h * N_NODES + grow] = ps[reg];
                    ad_out[(size_t)h * N_NODES + grow] = pd[reg];
                }
            }
        }
    }
}

// ================ K1: degree count || weight transpose/cast (independent) ================
__global__ __launch_bounds__(256) void k_count_prep(const int* __restrict__ edge,
                                                    int* __restrict__ cnt,
                                                    const float* __restrict__ W1,
                                                    __half* __restrict__ Wt1,
                                                    const float* __restrict__ W2,
                                                    __half* __restrict__ Wt2) {
    int t = blockIdx.x * 256 + threadIdx.x;
    int nthr = gridDim.x * 256;
    for (int e = t; e < N_EDGES_SL; e += nthr) {
        int d = (e < N_EDGES) ? edge[N_EDGES + e] : (e - N_EDGES);
        atomicAdd(&cnt[d], 1);
    }
    const int T1 = IN_CH * D1, T2 = D1 * OUT_CH;
    for (int idx = t; idx < T1 + T2; idx += nthr) {
        if (idx < T1) {
            int k = idx / D1, n = idx - k * D1;
            Wt1[(size_t)n * IN_CH + k] = __float2half(W1[idx]);
        } else {
            int i2 = idx - T1;
            int k = i2 / OUT_CH, n = i2 - k * OUT_CH;
            Wt2[(size_t)n * D1 + k] = __float2half(W2[i2]);
        }
    }
}

// ================ K2: layer-1 GEMM blocks || per-slice partial-sum blocks ================
// blocks [0, GEMM1_BLOCKS): MFMA GEMM wave-slots (parallel work).
// blocks [GEMM1_BLOCKS, +PART_BLOCKS): partial[b] = sum of cnt slice b (parallel work).
// No serial tail — the R9 single-block scan cost ~60 us of idle GPU.
__global__ __launch_bounds__(256) void k_gemm1p(const int* __restrict__ cnt,
                                                int* __restrict__ partial,
                                                const float* __restrict__ x,
                                                const __half* __restrict__ Wt1,
                                                __half* __restrict__ h1,
                                                const float* __restrict__ att_src1,
                                                const float* __restrict__ att_dst1,
                                                float* __restrict__ as1,
                                                float* __restrict__ ad1) {
    __shared__ int r4[4];
    int lane = threadIdx.x & 63, wv = threadIdx.x >> 6;
    if (blockIdx.x < GEMM1_BLOCKS) {
        int slot = blockIdx.x * 4 + wv;
        gemm_phase<HEADS1, float>(x, Wt1, h1, IN_CH, att_src1, att_dst1, as1, ad1,
                                  slot, GEMM1_BLOCKS * 4, lane);
    } else {
        int b = blockIdx.x - GEMM1_BLOCKS;
        int i = b * 256 + threadIdx.x;
        int v = (i < N_NODES) ? cnt[i] : 0;
#pragma unroll
        for (int off = 1; off < 64; off <<= 1) v += __shfl_xor(v, off, 64);
        if (lane == 0) r4[wv] = v;
        __syncthreads();
        if (threadIdx.x == 0) partial[b] = r4[0] + r4[1] + r4[2] + r4[3];
    }
}

// ================ K3: fully parallel scan -> row_ptr ================
// Each of the 118 blocks independently reduces partial[0..b-1] (118 ints, L2)
// for its prefix — no cross-block ordering — then block-scans its 256-slice.
__global__ __launch_bounds__(256) void k_scanwrite(const int* __restrict__ cnt,
                                                   const int* __restrict__ partial,
                                                   int* __restrict__ row_ptr) {
    __shared__ int spref;
    __shared__ int woff[4];
    int b = blockIdx.x, t = threadIdx.x;
    int lane = t & 63, wv = t >> 6;
    if (wv == 0) {
        int v = 0;
        if (lane < b) v += partial[lane];
        if (lane + 64 < b) v += partial[lane + 64];
#pragma unroll
        for (int off = 1; off < 64; off <<= 1) v += __shfl_xor(v, off, 64);
        if (lane == 0) spref = v;
    }
    int i = b * 256 + t;
    int v = (i < N_NODES) ? cnt[i] : 0;
    int inc = v;
#pragma unroll
    for (int off = 1; off < 64; off <<= 1) {
        int u = __shfl_up(inc, off, 64);
        if (lane >= off) inc += u;
    }
    if (lane == 63) woff[wv] = inc;
    __syncthreads(); // covers spref + woff
    int wb = 0;
#pragma unroll
    for (int k = 0; k < 4; ++k) wb += (k < wv) ? woff[k] : 0;
    int exc = spref + wb + inc - v;
    if (i < N_NODES) row_ptr[i] = exc;
    if (i == N_NODES - 1) row_ptr[N_NODES] = exc + v;
}

// ================ K4: scatter edges into CSR ================
__global__ __launch_bounds__(256) void k_scatter(const int* __restrict__ edge,
                                                 const int* __restrict__ row_ptr,
                                                 int* __restrict__ cursor,
                                                 int* __restrict__ esrc) {
    int e = blockIdx.x * blockDim.x + threadIdx.x;
    if (e >= N_EDGES_SL) return;
    int s, d;
    if (e < N_EDGES) { s = edge[e]; d = edge[N_EDGES + e]; }
    else { s = e - N_EDGES; d = s; }
    int pos = row_ptr[d] + atomicAdd(&cursor[d], 1);
    esrc[pos] = s;
}

// ================ fused softmax + weighted aggregate ================
// wave per (node,head), HEAD-MAJOR grid; scores HEAD-MAJOR [h][N].
// No max-subtract (inputs bounded; exp/sum identical). Weights PRE-NORMALIZED
// by r (w' = exp*r in [0,1]) packed to half2 in LDS once. Gather loop:
// lane = es*8+cg, 2 independent 16B loads/iter, __hfma2 fp16 accumulate.
// fp32 cross-sublane reduce via LDS pad-9 transpose -> 64-lane epilogue.
template<int NH, bool RELU>
__global__ __launch_bounds__(256) void k_attn_agg(const int* __restrict__ row_ptr,
                                                  const int* __restrict__ esrc,
                                                  const __half* __restrict__ hf,   // [N][NH*64]
                                                  const float* __restrict__ a_src, // [NH][N]
                                                  const float* __restrict__ a_dst, // [NH][N]
                                                  const float* __restrict__ bias,  // [NH*64]
                                                  __half* __restrict__ zout) {     // [N][NH*64]
    __shared__ unsigned wpk[4][64];
    __shared__ int jbuf[4][64];
    __shared__ float red[4][584];
    int wid = (blockIdx.x * 256 + threadIdx.x) >> 6;
    int lane = threadIdx.x & 63;
    int wv = threadIdx.x >> 6;
    if (wid >= N_NODES * NH) return;
    int h = wid / N_NODES;
    int node = wid - h * N_NODES;
    int start = row_ptr[node], end = row_ptr[node + 1];
    int deg = end - start;
    const float* asrc_h = a_src + (size_t)h * N_NODES;
    float adst = a_dst[(size_t)h * N_NODES + node];
    int es = lane >> 3, cg = lane & 7;
    const int RS = NH * 64;
    const __half* hbase = hf + h * 64 + cg * 8;
    __half2 acch[4] = {__half2{0, 0}, __half2{0, 0}, __half2{0, 0}, __half2{0, 0}};
    if (deg <= 64) {
        int j = 0;
        float ex = 0.f;
        if (lane < deg) {
            j = esrc[start + lane];
            ex = __expf(leaky(asrc_h[j] + adst));
        }
        float s = ex;
#pragma unroll
        for (int off = 1; off < 64; off <<= 1)
            s += __shfl_xor(s, off, 64);
        float r = 1.f / (s + 1e-16f);
        __half2 wn = __float2half2_rn(ex * r);
        wpk[wv][lane] = *(unsigned*)&wn;
        jbuf[wv][lane] = j;
        for (int k0 = 0; k0 < deg; k0 += 16) {
            int kA = k0 + es, kB = k0 + 8 + es;
            bool okA = kA < deg, okB = kB < deg;
            unsigned uA = okA ? wpk[wv][kA] : 0u;
            unsigned uB = okB ? wpk[wv][kB] : 0u;
            int jA = jbuf[wv][okA ? kA : 0];
            int jB = jbuf[wv][okB ? kB : 0];
            float4 vA = *(const float4*)(hbase + (size_t)jA * RS);
            float4 vB = *(const float4*)(hbase + (size_t)jB * RS);
            __half2 hwA = *(__half2*)&uA, hwB = *(__half2*)&uB;
            const __half2* pA = (const __half2*)&vA;
            const __half2* pB = (const __half2*)&vB;
#pragma unroll
            for (int i = 0; i < 4; ++i) {
                acch[i] = __hfma2(pA[i], hwA, acch[i]);
                acch[i] = __hfma2(pB[i], hwB, acch[i]);
            }
        }
    } else { // rare deg>64 path
        float s = 0.f;
        for (int k = start + lane; k < end; k += 64)
            s += __expf(leaky(asrc_h[esrc[k]] + adst));
#pragma unroll
        for (int off = 1; off < 64; off <<= 1)
            s += __shfl_xor(s, off, 64);
        float r = 1.f / (s + 1e-16f);
        for (int k0 = start; k0 < end; k0 += 16) {
            int kA = k0 + es, kB = k0 + 8 + es;
            bool okA = kA < end, okB = kB < end;
            int jA = esrc[okA ? kA : start];
            int jB = esrc[okB ? kB : start];
            float fA = okA ? __expf(leaky(asrc_h[jA] + adst)) * r : 0.f;
            float fB = okB ? __expf(leaky(asrc_h[jB] + adst)) * r : 0.f;
            __half2 hwA = __float2half2_rn(fA), hwB = __float2half2_rn(fB);
            float4 vA = *(const float4*)(hbase + (size_t)jA * RS);
            float4 vB = *(const float4*)(hbase + (size_t)jB * RS);
            const __half2* pA = (const __half2*)&vA;
            const __half2* pB = (const __half2*)&vB;
#pragma unroll
            for (int i = 0; i < 4; ++i) {
                acch[i] = __hfma2(pA[i], hwA, acch[i]);
                acch[i] = __hfma2(pB[i], hwB, acch[i]);
            }
        }
    }
#pragma unroll
    for (int i = 0; i < 4; ++i) {
        float2 f = __half22float2(acch[i]);
        red[wv][(cg * 8 + 2 * i) * 9 + es] = f.x;
        red[wv][(cg * 8 + 2 * i + 1) * 9 + es] = f.y;
    }
    float tot = 0.f;
#pragma unroll
    for (int e2 = 0; e2 < 8; ++e2)
        tot += red[wv][lane * 9 + e2];
    float o = tot + bias[h * 64 + lane];
    if (RELU) o = fmaxf(o, 0.f);
    zout[(size_t)node * RS + h * 64 + lane] = __float2half(o);
}

// ================ layer-2 GEMM (slot-strided, 256-thr blocks) ================
__global__ __launch_bounds__(256) void k_gemm2(const __half* __restrict__ z1,
                                               const __half* __restrict__ Wt2,
                                               __half* __restrict__ h2,
                                               const float* __restrict__ att_src2,
                                               const float* __restrict__ att_dst2,
                                               float* __restrict__ as2,
                                               float* __restrict__ ad2) {
    int lane = threadIdx.x & 63, wv = threadIdx.x >> 6;
    int slot = blockIdx.x * 4 + wv;
    int nsl = gridDim.x * 4;
    gemm_phase<1, __half>(z1, Wt2, h2, D1, att_src2, att_dst2, as2, ad2,
                          slot, nsl, lane);
}

// ================ decode: 8 lanes per edge, 16B fp16 loads, fdot2 ================
__global__ __launch_bounds__(256) void k_decode(const int* __restrict__ pos,
                                                const int* __restrict__ neg,
                                                const __half* __restrict__ z2,
                                                float* __restrict__ out) {
    int t = blockIdx.x * 256 + threadIdx.x;
    int e = t >> 3;
    int lc = t & 7;
    if (e >= 2 * PE_CNT) return;
    int a, b;
    if (e < PE_CNT) { a = pos[e]; b = pos[PE_CNT + e]; }
    else { int k = e - PE_CNT; a = neg[k]; b = neg[PE_CNT + k]; }
    union U { float4 f; f16x2 h[4]; __half2 hh[4]; } ua, ub;
    ua.f = *(const float4*)(z2 + (size_t)a * OUT_CH + lc * 8);
    ub.f = *(const float4*)(z2 + (size_t)b * OUT_CH + lc * 8);
    float v = 0.f;
#pragma unroll
    for (int i = 0; i < 4; ++i) {
#ifdef HAS_FDOT2
        v = __builtin_amdgcn_fdot2(ua.h[i], ub.h[i], v, false);
#else
        float2 fa = __half22float2(ua.hh[i]);
        float2 fb = __half22float2(ub.hh[i]);
        v += fa.x * fb.x + fa.y * fb.y;
#endif
    }
#pragma unroll
    for (int off = 1; off < 8; off <<= 1)
        v += __shfl_xor(v, off, 64);
    if (lc == 0) out[e] = v;
}

extern "C" void kernel_launch(void* const* d_in, const int* in_sizes, int n_in,
                              void* d_out, int out_size, void* d_ws, size_t ws_size,
                              hipStream_t stream) {
    const float* x        = (const float*)d_in[0];
    const int* edge_index = (const int*)d_in[1];
    const int* pos_ei     = (const int*)d_in[2];
    const int* neg_ei     = (const int*)d_in[3];
    const float* W1       = (const float*)d_in[4];
    const float* att_src1 = (const float*)d_in[5];
    const float* att_dst1 = (const float*)d_in[6];
    const float* b1       = (const float*)d_in[7];
    const float* W2       = (const float*)d_in[8];
    const float* att_src2 = (const float*)d_in[9];
    const float* att_dst2 = (const float*)d_in[10];
    const float* b2       = (const float*)d_in[11];
    float* out            = (float*)d_out;

    char* ws = (char*)d_ws;
    size_t off = 0;
    auto alloc = [&](size_t bytes) -> void* {
        void* p = ws + off;
        off = (off + bytes + 255) & ~(size_t)255;
        return p;
    };
    int* cnt     = (int*)alloc(sizeof(int) * (size_t)2 * N_NODES); // cnt+cursor: one memset
    int* cursor  = cnt + N_NODES;
    int* partial = (int*)alloc(sizeof(int) * PART_BLOCKS);
    int* row_ptr = (int*)alloc(sizeof(int) * (N_NODES + 1));
    int* esrc    = (int*)alloc(sizeof(int) * (size_t)N_EDGES_SL);
    __half* h1   = (__half*)alloc(sizeof(__half) * (size_t)N_NODES * D1);
    __half* z1   = (__half*)alloc(sizeof(__half) * (size_t)N_NODES * D1);
    __half* h2   = (__half*)alloc(sizeof(__half) * (size_t)N_NODES * OUT_CH);
    __half* z2   = (__half*)alloc(sizeof(__half) * (size_t)N_NODES * OUT_CH);
    __half* Wt1  = (__half*)alloc(sizeof(__half) * (size_t)D1 * IN_CH);
    __half* Wt2  = (__half*)alloc(sizeof(__half) * (size_t)OUT_CH * D1);
    float* as1   = (float*)alloc(sizeof(float) * (size_t)N_NODES * HEADS1); // [h][N]
    float* ad1   = (float*)alloc(sizeof(float) * (size_t)N_NODES * HEADS1); // [h][N]
    float* as2   = (float*)alloc(sizeof(float) * (size_t)N_NODES);
    float* ad2   = (float*)alloc(sizeof(float) * (size_t)N_NODES);

    hipMemsetAsync(cnt, 0, sizeof(int) * (size_t)2 * N_NODES, stream);
    // K1: degree count || weight prep
    k_count_prep<<<512, 256, 0, stream>>>(edge_index, cnt, W1, Wt1, W2, Wt2);
    // K2: layer-1 MFMA GEMM + scores || cnt partial sums (all-parallel)
    k_gemm1p<<<GEMM1_BLOCKS + PART_BLOCKS, 256, 0, stream>>>(
        cnt, partial, x, Wt1, h1, att_src1, att_dst1, as1, ad1);
    // K3: parallel scan -> row_ptr
    k_scanwrite<<<PART_BLOCKS, 256, 0, stream>>>(cnt, partial, row_ptr);
    // K4: scatter edges
    k_scatter<<<(N_EDGES_SL + 255) / 256, 256, 0, stream>>>(edge_index, row_ptr, cursor, esrc);
    // layer-1 softmax-aggregate (+relu)
    k_attn_agg<HEADS1, true><<<(N_NODES * HEADS1 + 3) / 4, 256, 0, stream>>>(
        row_ptr, esrc, h1, as1, ad1, b1, z1);
    // layer-2 GEMM + scores
    k_gemm2<<<469, 256, 0, stream>>>(z1, Wt2, h2, att_src2, att_dst2, as2, ad2);
    // layer-2 softmax-aggregate
    k_attn_agg<1, false><<<(N_NODES + 3) / 4, 256, 0, stream>>>(
        row_ptr, esrc, h2, as2, ad2, b2, z2);
    // decode
    k_decode<<<(2 * PE_CNT * 8 + 255) / 256, 256, 0, stream>>>(pos_ei, neg_ei, z2, out);

    (void)in_sizes; (void)n_in; (void)out_size; (void)ws_size;
}